// Round 11
// baseline (64.968 us; speedup 1.0000x reference)
//
#include <hip/hip_runtime.h>
#include <hip/hip_fp16.h>
#include <math.h>

constexpr int B    = 512;
constexpr int NIN  = 1024;
constexpr int NK   = 128;
constexpr int DK   = 5;
constexpr int NF   = 640;         // theta row stride (128*5)
constexpr int NOUT = 1152;
constexpr int LDB  = 40;          // Bxh row stride in halves (32 + 8 pad)
constexpr int LDA  = 1040;        // Ath row stride in halves (1024 + 16 pad)
#define LOG2E 1.44269504088896f

typedef _Float16 f16x4 __attribute__((ext_vector_type(4)));
typedef _Float16 f16x8 __attribute__((ext_vector_type(8)));
typedef float    f32x4 __attribute__((ext_vector_type(4)));

// ---------------------------------------------------------------------------
// ONE kernel, 128 blocks (one per k) x 1024 threads (16 waves, 1 block/CU).
//  1. copy x rows 4k..4k+3 to out (passthrough)
//  2. stage theta[:,k,:] -> Ath[5][1024] f16; theta^2 shuffle-reduce -> s_d
//  3. K-loop: 32 chunks of 32 k: stage x[512][32] f32->f16 (double-buffered),
//     MFMA (A rows 5..15 = zero via predicated fragment) -> acc[16n][512b]
//  4. a16s[5][512] = f16(acc * s_d)   (overlays Ath — dead after loop)
//  5. pairwise: f[b,k] = sum_b' exp2(-sum_d |a-a'|) - 1 + bias[k]
// actv NEVER leaves the CU: no partials buffer, no workspace, one dispatch.
// ---------------------------------------------------------------------------
__global__ __launch_bounds__(1024) void fused_kernel(
        const float* __restrict__ x,       // [512][1024]
        const float* __restrict__ theta,   // [1024][640]
        const float* __restrict__ lws,     // [640]
        const float* __restrict__ bias,    // [128]
        float* __restrict__ out) {         // [512][1152]
    __shared__ __align__(16) _Float16 Ath[DK * LDA];      // 10400 B
    __shared__ __align__(16) _Float16 Bxh[2][512 * LDB];  // 81920 B
    __shared__ float wred[16][DK];
    __shared__ float s_sh[DK];

    __half* a16s = (__half*)&Ath[0];                   // 5120 B overlay
    float*  red  = (float*)((char*)&Ath[0] + 5376);    // 4096 B overlay

    const int t = threadIdx.x;
    const int k = blockIdx.x;

    // ---- 1. x passthrough: this block owns rows 4k..4k+3 ----
    {
        const int row = 4 * k + (t >> 8);
        const int c4  = t & 255;
        ((float4*)out)[row * (NOUT / 4) + c4] =
            ((const float4*)x)[row * (NIN / 4) + c4];
    }

    // ---- 2. theta slab stage + theta^2 wave reduce ----
    {
        const float* tp = theta + (size_t)t * NF + k * DK;
        float th[DK], sq[DK];
        #pragma unroll
        for (int d = 0; d < DK; ++d) { th[d] = tp[d]; sq[d] = th[d] * th[d]; }
        #pragma unroll
        for (int d = 0; d < DK; ++d) Ath[d * LDA + t] = (_Float16)th[d];
        #pragma unroll
        for (int d = 0; d < DK; ++d) {
            #pragma unroll
            for (int m = 32; m >= 1; m >>= 1) sq[d] += __shfl_xor(sq[d], m, 64);
        }
        if ((t & 63) == 0) {
            #pragma unroll
            for (int d = 0; d < DK; ++d) wred[t >> 6][d] = sq[d];
        }
    }

    // ---- 3a. stage x chunk 0 ----
    {
        const int f4i = t & 7;
        #pragma unroll
        for (int p = 0; p < 4; ++p) {
            const int row = (t >> 3) + p * 128;
            const float4 v = *(const float4*)&x[(size_t)row * NIN + f4i * 4];
            f16x4 h;
            h[0] = (_Float16)v.x; h[1] = (_Float16)v.y;
            h[2] = (_Float16)v.z; h[3] = (_Float16)v.w;
            *(f16x4*)&Bxh[0][row * LDB + f4i * 4] = h;
        }
    }
    __syncthreads();

    if (t < DK) {
        float nrm = 0.f;
        #pragma unroll
        for (int w = 0; w < 16; ++w) nrm += wred[w][t];
        s_sh[t] = __expf(lws[k * DK + t]) * rsqrtf(nrm) * LOG2E;
    }

    // ---- 3b. K loop: 32 chunks, double-buffered ----
    const int wv  = t >> 6;
    const int l   = t & 63;
    const int r16 = l & 15;
    const int kg  = l >> 4;

    f32x4 acc0 = {0.f, 0.f, 0.f, 0.f};
    f32x4 acc1 = {0.f, 0.f, 0.f, 0.f};

    for (int c = 0; c < 32; ++c) {
        float4 nx[4];
        if (c < 31) {
            const int f4i = t & 7;
            #pragma unroll
            for (int p = 0; p < 4; ++p) {
                const int row = (t >> 3) + p * 128;
                nx[p] = *(const float4*)&x[(size_t)row * NIN + (c + 1) * 32 + f4i * 4];
            }
        }
        {
            f16x8 av = {0, 0, 0, 0, 0, 0, 0, 0};
            if (r16 < DK)
                av = *(const f16x8*)&Ath[r16 * LDA + c * 32 + kg * 8];
            const f16x8 bv0 = *(const f16x8*)&Bxh[c & 1][(wv * 32      + r16) * LDB + kg * 8];
            const f16x8 bv1 = *(const f16x8*)&Bxh[c & 1][(wv * 32 + 16 + r16) * LDB + kg * 8];
            acc0 = __builtin_amdgcn_mfma_f32_16x16x32_f16(av, bv0, acc0, 0, 0, 0);
            acc1 = __builtin_amdgcn_mfma_f32_16x16x32_f16(av, bv1, acc1, 0, 0, 0);
        }
        __syncthreads();
        if (c < 31) {
            const int f4i = t & 7;
            #pragma unroll
            for (int p = 0; p < 4; ++p) {
                const int row = (t >> 3) + p * 128;
                f16x4 h;
                h[0] = (_Float16)nx[p].x; h[1] = (_Float16)nx[p].y;
                h[2] = (_Float16)nx[p].z; h[3] = (_Float16)nx[p].w;
                *(f16x4*)&Bxh[(c + 1) & 1][row * LDB + f4i * 4] = h;
            }
        }
        __syncthreads();
    }

    // ---- 4. epilogue: a16s[d][b] = f16(acc * s_d) ----
    // C map: col(b) = lane&15, row(n) = kg*4 + j  [m89/m91]; rows 5..15 = 0.
    {
        const int c0 = wv * 32 + r16;
        if (kg == 0) {
            #pragma unroll
            for (int j = 0; j < 4; ++j) {
                a16s[j * B + c0]      = __float2half(acc0[j] * s_sh[j]);
                a16s[j * B + c0 + 16] = __float2half(acc1[j] * s_sh[j]);
            }
        } else if (kg == 1) {
            a16s[4 * B + c0]      = __float2half(acc0[0] * s_sh[4]);
            a16s[4 * B + c0 + 16] = __float2half(acc1[0] * s_sh[4]);
        }
    }
    __syncthreads();

    // ---- 5. pairwise: thread t -> b = t&511, b'-half h = t>>9 ----
    const int b = t & 511;
    const int h = t >> 9;

    __half2 A2[DK];
    #pragma unroll
    for (int d = 0; d < DK; ++d) A2[d] = __half2half2(a16s[d * B + b]);

    typedef _Float16 f16x2v __attribute__((ext_vector_type(2)));
    union HV { __half2 h; f16x2v v; };
    union W8 { f16x8 v; __half2 h[4]; };
    const HV ones = {__half2half2(__float2half(1.0f))};

    float acc = 0.f;
    const int bp0 = h * 256;
    #pragma unroll 2
    for (int m = 0; m < 32; ++m) {
        const int bp = bp0 + m * 8;        // wave-uniform -> LDS b128 broadcast
        W8 w0, w1, w2, w3, w4;
        w0.v = *(const f16x8*)(a16s + 0 * B + bp);
        w1.v = *(const f16x8*)(a16s + 1 * B + bp);
        w2.v = *(const f16x8*)(a16s + 2 * B + bp);
        w3.v = *(const f16x8*)(a16s + 3 * B + bp);
        w4.v = *(const f16x8*)(a16s + 4 * B + bp);
        #pragma unroll
        for (int cc = 0; cc < 4; ++cc) {
            __half2 dA = __habs2(__hsub2(A2[0], w0.h[cc]));
            dA = __hadd2(dA, __habs2(__hsub2(A2[1], w1.h[cc])));
            dA = __hadd2(dA, __habs2(__hsub2(A2[2], w2.h[cc])));
            dA = __hadd2(dA, __habs2(__hsub2(A2[3], w3.h[cc])));
            dA = __hadd2(dA, __habs2(__hsub2(A2[4], w4.h[cc])));
            HV eA; eA.h = h2exp2(__hneg2(dA));
#if __has_builtin(__builtin_amdgcn_fdot2)
            acc = __builtin_amdgcn_fdot2(eA.v, ones.v, acc, false);
#else
            acc += __low2float(eA.h) + __high2float(eA.h);
#endif
        }
    }
    red[h * B + b] = acc;
    __syncthreads();
    if (t < B) {
        const float f = red[t] + red[B + t] - 1.0f + bias[k];
        out[(size_t)t * NOUT + NIN + k] = f;
    }
}

// ---------------------------------------------------------------------------
extern "C" void kernel_launch(void* const* d_in, const int* in_sizes, int n_in,
                              void* d_out, int out_size, void* d_ws, size_t ws_size,
                              hipStream_t stream) {
    const float* x     = (const float*)d_in[0];   // [512,1024]
    const float* theta = (const float*)d_in[1];   // [1024,128,5]
    const float* lws   = (const float*)d_in[2];   // [128,5]
    const float* bias  = (const float*)d_in[3];   // [128]
    float* out = (float*)d_out;                   // [512,1152]

    fused_kernel<<<dim3(NK), 1024, 0, stream>>>(x, theta, lws, bias, out);
}

// Round 12
// 26.789 us; speedup vs baseline: 2.4252x; 2.4252x over previous
//
#include <hip/hip_runtime.h>
#include <hip/hip_fp16.h>
#include <math.h>

constexpr int B    = 512;
constexpr int NIN  = 1024;
constexpr int NK   = 128;
constexpr int DK   = 5;
constexpr int NF   = NK * DK;     // 640 flattened kernel columns
constexpr int NOUT = NIN + NK;    // 1152
constexpr int SPLITK = 8;         // K chunks (128 each)
constexpr int LDA = 136;          // LDS row stride in halves (128 + 8 pad)
#define LOG2E 1.44269504088896f

typedef _Float16 f16x4 __attribute__((ext_vector_type(4)));
typedef _Float16 f16x8 __attribute__((ext_vector_type(8)));
typedef float    f32x4 __attribute__((ext_vector_type(4)));

// ---------------------------------------------------------------------------
// Kernel 1: split-K MFMA GEMM (UNCHANGED from R10).
//   grid 1280 = (20 n-tiles x 8 b-tiles) x 8 z; 256 thr = 4 waves.
// ---------------------------------------------------------------------------
__global__ __launch_bounds__(256) void gemm_kernel(
        const float* __restrict__ x,       // [512][1024]
        const float* __restrict__ theta,   // [1024][640]
        __half* __restrict__ actvP16,      // [8][640][512]
        float* __restrict__ ps) {          // [8][640]
    __shared__ _Float16 Ath[32 * LDA];     // theta^T tile [n][k]
    __shared__ _Float16 Bxh[64 * LDA];     // x tile [b][k]
    __shared__ float    red2[32][33];

    const int t    = threadIdx.x;
    const int tile = blockIdx.x >> 3;
    const int z    = blockIdx.x & 7;
    const int nt   = tile >> 3;            // 0..19
    const int bt   = tile & 7;             // 0..7
    const int n0   = nt * 32;
    const int b0   = bt * 64;
    const bool do_ps = (bt == 0);
    const int kw   = z * 128;

    const int kq = t >> 3;                 // 0..31, k-rows kq*4..+3
    const int nc = (t & 7) * 4;            // 4 n-cols
    float4 tv0 = *(const float4*)&theta[(kw + kq*4 + 0) * NF + n0 + nc];
    float4 tv1 = *(const float4*)&theta[(kw + kq*4 + 1) * NF + n0 + nc];
    float4 tv2 = *(const float4*)&theta[(kw + kq*4 + 2) * NF + n0 + nc];
    float4 tv3 = *(const float4*)&theta[(kw + kq*4 + 3) * NF + n0 + nc];

    const int br = t >> 2;                 // 0..63
    const int ki = t & 3;
    float4 xv[8];
    #pragma unroll
    for (int i = 0; i < 8; ++i)
        xv[i] = *(const float4*)&x[(b0 + br) * NIN + kw + (ki + i * 4) * 4];

    if (do_ps) {
        red2[kq][nc + 0] = tv0.x*tv0.x + tv1.x*tv1.x + tv2.x*tv2.x + tv3.x*tv3.x;
        red2[kq][nc + 1] = tv0.y*tv0.y + tv1.y*tv1.y + tv2.y*tv2.y + tv3.y*tv3.y;
        red2[kq][nc + 2] = tv0.z*tv0.z + tv1.z*tv1.z + tv2.z*tv2.z + tv3.z*tv3.z;
        red2[kq][nc + 3] = tv0.w*tv0.w + tv1.w*tv1.w + tv2.w*tv2.w + tv3.w*tv3.w;
    }

    {
        f16x4 h;
        h[0]=(_Float16)tv0.x; h[1]=(_Float16)tv1.x; h[2]=(_Float16)tv2.x; h[3]=(_Float16)tv3.x;
        *(f16x4*)&Ath[(nc + 0) * LDA + kq * 4] = h;
        h[0]=(_Float16)tv0.y; h[1]=(_Float16)tv1.y; h[2]=(_Float16)tv2.y; h[3]=(_Float16)tv3.y;
        *(f16x4*)&Ath[(nc + 1) * LDA + kq * 4] = h;
        h[0]=(_Float16)tv0.z; h[1]=(_Float16)tv1.z; h[2]=(_Float16)tv2.z; h[3]=(_Float16)tv3.z;
        *(f16x4*)&Ath[(nc + 2) * LDA + kq * 4] = h;
        h[0]=(_Float16)tv0.w; h[1]=(_Float16)tv1.w; h[2]=(_Float16)tv2.w; h[3]=(_Float16)tv3.w;
        *(f16x4*)&Ath[(nc + 3) * LDA + kq * 4] = h;
    }
    #pragma unroll
    for (int i = 0; i < 8; ++i) {
        f16x4 h;
        h[0] = (_Float16)xv[i].x;  h[1] = (_Float16)xv[i].y;
        h[2] = (_Float16)xv[i].z;  h[3] = (_Float16)xv[i].w;
        *(f16x4*)&Bxh[br * LDA + (ki + i * 4) * 4] = h;
    }
    __syncthreads();

    const int w   = t >> 6;
    const int l   = t & 63;
    const int r16 = l & 15;
    const int kg  = l >> 4;

    f32x4 acc0 = {0.f,0.f,0.f,0.f}, acc1 = {0.f,0.f,0.f,0.f};
    #pragma unroll
    for (int ks = 0; ks < 4; ++ks) {
        const f16x8 bv  = *(const f16x8*)&Bxh[(w*16 + r16)*LDA + ks*32 + kg*8];
        const f16x8 av0 = *(const f16x8*)&Ath[( 0 + r16)*LDA + ks*32 + kg*8];
        const f16x8 av1 = *(const f16x8*)&Ath[(16 + r16)*LDA + ks*32 + kg*8];
        acc0 = __builtin_amdgcn_mfma_f32_16x16x32_f16(av0, bv, acc0, 0, 0, 0);
        acc1 = __builtin_amdgcn_mfma_f32_16x16x32_f16(av1, bv, acc1, 0, 0, 0);
    }

    {
        __half* dst = actvP16 + (size_t)z * NF * B
                    + (size_t)(n0 + kg*4) * B + b0 + w*16 + r16;
        #pragma unroll
        for (int j = 0; j < 4; ++j) {
            dst[j*B]          = __float2half(acc0[j]);
            dst[(16 + j) * B] = __float2half(acc1[j]);
        }
    }
    if (do_ps) {
        __syncthreads();
        if (t < 32) {
            float tot = 0.f;
            #pragma unroll
            for (int rr = 0; rr < 32; ++rr) tot += red2[rr][t];
            ps[z * NF + n0 + t] = tot;
        }
    }
}

// ---------------------------------------------------------------------------
// Kernel 2: split-K reduce + scale -> final a16.
//   a16[n][b] = f16( (sum_z actvP16[z][n][b]) * exp(lws[n])*rsqrt(sum ps)*log2e )
// grid 160 x 256: thread = one f16x8 unit (row = u>>6, col8 = (u&63)*8).
// ---------------------------------------------------------------------------
__global__ __launch_bounds__(256) void rs_kernel(
        const __half* __restrict__ actvP16,// [8][640][512]
        const float* __restrict__ ps,      // [8][640]
        const float* __restrict__ lws,     // [640]
        __half* __restrict__ a16) {        // [640][512]
    const int u   = blockIdx.x * 256 + threadIdx.x;   // 0..40959
    const int row = u >> 6;
    const int c8  = (u & 63) * 8;

    float nrm = 0.f;
    #pragma unroll
    for (int z = 0; z < SPLITK; ++z) nrm += ps[z * NF + row];
    const float s = __expf(lws[row]) * rsqrtf(nrm) * LOG2E;

    float accf[8];
    #pragma unroll
    for (int i = 0; i < 8; ++i) accf[i] = 0.f;
    const __half* p = actvP16 + (size_t)row * B + c8;
    #pragma unroll
    for (int z = 0; z < SPLITK; ++z) {
        const f16x8 v = *(const f16x8*)(p + (size_t)z * NF * B);
        #pragma unroll
        for (int i = 0; i < 8; ++i) accf[i] += (float)v[i];
    }
    f16x8 h;
    #pragma unroll
    for (int i = 0; i < 8; ++i) h[i] = (_Float16)(accf[i] * s);
    *(f16x8*)&a16[(size_t)row * B + c8] = h;
}

// ---------------------------------------------------------------------------
// Kernel 3: pairwise finish — packed-f16 distance, f32 exp (v_exp_f32 only).
//   f[b,k] = sum_{b'} exp2(-sum_d |a16[d,b]-a16[d,b']|) - 1 + bias[k]
// grid (128 k, 8 e) x 256 thr (4 blocks/CU, 16 waves/CU).
// thread: row ba = e*64 + (t&63); b'-quarter g = t>>6 (128 b' each).
// ---------------------------------------------------------------------------
__global__ __launch_bounds__(256) void pairwise_kernel(
        const __half* __restrict__ a16,    // [640][512]
        const float* __restrict__ bias,    // [128]
        const float* __restrict__ x,       // [512][1024]
        float* __restrict__ out) {         // [512][1152]
    __shared__ __half a16s[DK * B];        // 5120 B
    __shared__ float  red[4 * 64];

    const int k = blockIdx.x;
    const int e = blockIdx.y;              // b-eighth (0..7)
    const int t = threadIdx.x;

    // fused x passthrough: 4 of the 8 blocks per k copy one row each
    if (e < 4) {
        const int row = k * 4 + e;
        ((float4*)out)[row * (NOUT/4) + t] = ((const float4*)x)[row * (NIN/4) + t];
    }

    // stage the k-slab (5 rows x 512 halves = 320 x 16B)
    {
        const uint4* src = (const uint4*)(a16 + (size_t)k * DK * B);
        ((uint4*)a16s)[t] = src[t];
        if (t < 64) ((uint4*)a16s)[256 + t] = src[256 + t];
    }
    __syncthreads();

    const int g  = t >> 6;                 // wave-uniform b' quarter (0..3)
    const int r  = t & 63;
    const int ba = e * 64 + r;

    __half2 A2[DK];
    #pragma unroll
    for (int d = 0; d < DK; ++d) A2[d] = __half2half2(a16s[d * B + ba]);

    union W8 { f16x8 v; __half2 h[4]; };

    float acc = 0.f;
    const int bp0 = g * 128;
    #pragma unroll 2
    for (int m = 0; m < 16; ++m) {
        const int bp = bp0 + m * 8;        // wave-uniform -> LDS b128 broadcast
        W8 w0, w1, w2, w3, w4;
        w0.v = *(const f16x8*)&a16s[0*B + bp];
        w1.v = *(const f16x8*)&a16s[1*B + bp];
        w2.v = *(const f16x8*)&a16s[2*B + bp];
        w3.v = *(const f16x8*)&a16s[3*B + bp];
        w4.v = *(const f16x8*)&a16s[4*B + bp];
        #pragma unroll
        for (int c = 0; c < 4; ++c) {
            __half2 dA = __habs2(__hsub2(A2[0], w0.h[c]));
            dA = __hadd2(dA, __habs2(__hsub2(A2[1], w1.h[c])));
            dA = __hadd2(dA, __habs2(__hsub2(A2[2], w2.h[c])));
            dA = __hadd2(dA, __habs2(__hsub2(A2[3], w3.h[c])));
            dA = __hadd2(dA, __habs2(__hsub2(A2[4], w4.h[c])));
            // f32 exp path: v_cvt_f32_f16 x2 + v_exp_f32 (neg modifier) x2
            const float lo = __low2float(dA);
            const float hi = __high2float(dA);
            acc += __builtin_amdgcn_exp2f(-lo);
            acc += __builtin_amdgcn_exp2f(-hi);
        }
    }
    red[g * 64 + r] = acc;
    __syncthreads();
    if (t < 64) {
        const float f = ((red[t] + red[64 + t]) + (red[128 + t] + red[192 + t]))
                        - 1.0f + bias[k];
        out[(e * 64 + t) * NOUT + NIN + k] = f;
    }
}

// ---------------------------------------------------------------------------
extern "C" void kernel_launch(void* const* d_in, const int* in_sizes, int n_in,
                              void* d_out, int out_size, void* d_ws, size_t ws_size,
                              hipStream_t stream) {
    const float* x     = (const float*)d_in[0];   // [512,1024]
    const float* theta = (const float*)d_in[1];   // [1024,128,5]
    const float* lws   = (const float*)d_in[2];   // [128,5]
    const float* bias  = (const float*)d_in[3];   // [128]
    float* out = (float*)d_out;                   // [512,1152]

    // ws layout: ps @0 (64KB pad), actvP16 @64KB (5.24MB), a16 after (0.65MB)
    char* wsb = (char*)d_ws;
    float*  ps      = (float*)wsb;
    __half* actvP16 = (__half*)(wsb + (64 << 10));
    __half* a16     = (__half*)(wsb + (64 << 10) + (size_t)SPLITK * 2 * NF * B);

    gemm_kernel<<<dim3(1280), 256, 0, stream>>>(x, theta, actvP16, ps);
    rs_kernel<<<dim3(160), 256, 0, stream>>>(actvP16, ps, lws, a16);
    pairwise_kernel<<<dim3(NK, 8), 256, 0, stream>>>(a16, bias, x, out);
}